// Round 10
// baseline (593.091 us; speedup 1.0000x reference)
//
#include <hip/hip_runtime.h>
#include <cmath>

typedef __attribute__((ext_vector_type(8))) short bf16x8;
typedef __attribute__((ext_vector_type(4))) float f32x4;
typedef unsigned short u16;

struct __align__(8) us4 { u16 x, y, z, w; };

__device__ __forceinline__ u16 f2bf(float f) {
    union { float f; unsigned u; } v; v.f = f;
    unsigned u = v.u;
    u += 0x7fffu + ((u >> 16) & 1u);   // RNE
    return (u16)(u >> 16);
}
__device__ __forceinline__ float bf2f(u16 h) {
    union { unsigned u; float f; } v; v.u = ((unsigned)h) << 16;
    return v.f;
}
__device__ __forceinline__ float fast_tanh(float x) {
    // tanh(x) = sign(x) * (1 - t)/(1 + t), t = exp(-2|x|)  (t in (0,1]; no inf path)
    float t = __expf(-2.f * fabsf(x));
    float th = (1.f - t) / (1.f + t);
    return copysignf(th, x);
}
__device__ __forceinline__ f32x4 mfma16(bf16x8 a, bf16x8 b, f32x4 c) {
    return __builtin_amdgcn_mfma_f32_16x16x32_bf16(a, b, c, 0, 0, 0);
}
__device__ __forceinline__ void ld_lds16(const u16* g, u16* l) {
    __builtin_amdgcn_global_load_lds(
        (const __attribute__((address_space(1))) unsigned int*)g,
        (__attribute__((address_space(3))) unsigned int*)l, 16, 0, 0);
}

// ---------------- x -> CatA right half (bf16) + zero qv/kv ----------------
__global__ __launch_bounds__(256) void cvtx(const float* __restrict__ in,
                                            u16* __restrict__ CatA, float* __restrict__ qkz) {
    int i = blockIdx.x * 256 + threadIdx.x;         // over 3145728 float4 groups
    float4 f = reinterpret_cast<const float4*>(in)[i];
    us4 o; o.x = f2bf(f.x); o.y = f2bf(f.y); o.z = f2bf(f.z); o.w = f2bf(f.w);
    int row = i / 192, col = (i % 192) * 4;
    *reinterpret_cast<us4*>(CatA + (size_t)row * 1536 + 768 + col) = o;
    if (i < 8192) reinterpret_cast<float4*>(qkz)[i] = float4{0.f, 0.f, 0.f, 0.f};
}

// ---------------- 7 weight converts in one dispatch ----------------
struct WCvt { const float* s[7]; u16* d[7]; int ld[7]; };
__global__ __launch_bounds__(256) void cvtw(WCvt w) {
    int wi = blockIdx.y;
    int i = blockIdx.x * 256 + threadIdx.x;         // over 147456 float4 groups
    float4 f = reinterpret_cast<const float4*>(w.s[wi])[i];
    us4 o; o.x = f2bf(f.x); o.y = f2bf(f.y); o.z = f2bf(f.z); o.w = f2bf(f.w);
    int row = i / 192, col = (i % 192) * 4;
    *reinterpret_cast<us4*>(w.d[wi] + (size_t)row * w.ld[wi] + col) = o;
}

// =====================================================================
// Round 10: LDS-BW theory test. The frozen 2-barrier loop is LDS-read
// bound: 128^2 tile, 2x2 waves reads (128*2+128*2)*BK*2B = 64KB LDS per
// K-step vs 160cyc/SIMD MFMA -> cap ~33% (matches 5 rounds of data).
// Change: BM=256 x BN=128, SAME 2x2 wave grid (per-wave 128x64,
// acc[8][4]): LDS bytes/FLOP 0.031 -> 0.023 (-25%). Same barriers,
// same swizzle, same staging pattern (8A+4B gload_lds), 48KB LDS.
// Cost: ~218 regs -> 2 blk/CU. Accumulation order per output element
// bit-identical (absmax canary 0.0234375).
// Predict: gGATES 103.5 -> 80-90us, MfmaUtil 33 -> 38-44%. If >=100us
// at <=34%: theory falsified -> revert r6, declare plateau.
// =====================================================================
enum { EPI_FPT = 0, EPI_Y, EPI_GATES, EPI_OUT };

struct Epi {
    const float* b1; const float* b2; const float* b3; const float* b4;
    const float* wq; const float* wk; float* qv; float* kv;   // FPT
    u16* fpT;
    u16* catA;                                                 // Y
    const u16* xb;        // CatA+768 (stride 1536)
    u16* ub_o; u16* rxb_o;                                     // GATES
    const u16* ub; float* of;                                  // OUT
};

template<int EPI, int PH>
__device__ __forceinline__ void g_body(
    const u16* __restrict__ A1, const u16* __restrict__ B1,
    const u16* __restrict__ A2, const u16* __restrict__ B2,
    int K, int ldA1, int ldB1, int ldA2, int ldB2,
    size_t zA, size_t zB, Epi e)
{
    __shared__ u16 lA[256 * 64];   // 32 KB
    __shared__ u16 lB[128 * 64];   // 16 KB

    const int t = threadIdx.x;
    const int w = t >> 6, lane = t & 63, lm = lane & 15, quad = lane >> 4;
    const int row0 = blockIdx.x * 256;
    int col0, grp = 0;
    if constexpr (EPI == EPI_GATES) { grp = blockIdx.y / 6; col0 = (blockIdx.y % 6) * 128; }
    else col0 = blockIdx.y * 128;

    // staging: linear chunk-id n = q*256 + t; LDS offset = n*16B (fits
    // wave-uniform base + lane*16). Global: row = q*32 + (t>>3),
    // chunk = (t&7) ^ ((t>>3)&7)  [XOR swizzle vs row&7] — row&7 ==
    // (t>>3)&7 for every q since q*32 is a multiple of 8.
    const int rs2 = t >> 3;                         // 0..31
    const int kc2 = (((t & 7) ^ (rs2 & 7)) * 8);
    u16* dA_[8]; u16* dB_[4];
#pragma unroll
    for (int q = 0; q < 8; q++) dA_[q] = lA + q * 2048 + w * 512;
#pragma unroll
    for (int q = 0; q < 4; q++) dB_[q] = lB + q * 2048 + w * 512;

    // compute map: wave (w&1) row-half (128 rows), (w>>1) col-half (64 cols)
    const int rw0 = (w & 1) * 128, cw0 = (w >> 1) * 64;
    // LDS read: row R, logical k-half h chunk (quad+4h); stored at chunk^(R&7), R&7 == lm&7
    const int ch0 = ((quad) ^ (lm & 7)) * 8;
    const int ch1 = ((quad + 4) ^ (lm & 7)) * 8;
    int laB[8], lbB[4];
#pragma unroll
    for (int i = 0; i < 8; i++) laB[i] = (rw0 + i * 16 + lm) * 64;
#pragma unroll
    for (int j = 0; j < 4; j++) lbB[j] = (cw0 + j * 16 + lm) * 64;

    f32x4 acc[8][4] = {};
    bool first = true;

#pragma unroll
    for (int ph = 0; ph < PH; ph++) {
        const u16* As; const u16* Bs; int ldA, ldB;
        if (ph == 0) { As = A1 + (size_t)blockIdx.z * zA; Bs = B1 + (size_t)blockIdx.z * zB; ldA = ldA1; ldB = ldB1; }
        else         { As = A2; Bs = B2; ldA = ldA2; ldB = ldB2; }
        if constexpr (EPI == EPI_GATES) Bs += (size_t)grp * (768 * 1536);
        const u16* gA = As + (size_t)(row0 + rs2) * ldA + kc2;
        const u16* gB = Bs + (size_t)(col0 + rs2) * ldB + kc2;

        for (int k0 = 0; k0 < K; k0 += 64) {
            if (!first) __syncthreads();
            first = false;
#pragma unroll
            for (int q = 0; q < 8; q++)
                ld_lds16(gA + (size_t)(q * 32) * ldA + k0, dA_[q]);
#pragma unroll
            for (int q = 0; q < 4; q++)
                ld_lds16(gB + (size_t)(q * 32) * ldB + k0, dB_[q]);
            __syncthreads();

#pragma unroll
            for (int h = 0; h < 2; h++) {
                const int ch = h ? ch1 : ch0;
                bf16x8 a[8], b[4];
#pragma unroll
                for (int i = 0; i < 8; i++) a[i] = *reinterpret_cast<const bf16x8*>(lA + laB[i] + ch);
#pragma unroll
                for (int j = 0; j < 4; j++) b[j] = *reinterpret_cast<const bf16x8*>(lB + lbB[j] + ch);
#pragma unroll
                for (int i = 0; i < 8; i++)
#pragma unroll
                    for (int j = 0; j < 4; j++)
                        acc[i][j] = mfma16(a[i], b[j], acc[i][j]);
            }
        }
    }

    // ---------------- epilogue ----------------
#pragma unroll
    for (int i = 0; i < 8; i++) {
        const int gr = row0 + rw0 + i * 16 + quad * 4;   // local (per-z) row
        if constexpr (EPI == EPI_FPT) {
            float qp[4] = {}, kp[4] = {};
            int bb = gr >> 10, nn = gr & 1023;
#pragma unroll
            for (int j = 0; j < 4; j++) {
                int gc = col0 + cw0 + j * 16 + lm;
                float bias = e.b1[gc];
                float v0 = acc[i][j][0] + bias, v1 = acc[i][j][1] + bias;
                float v2 = acc[i][j][2] + bias, v3 = acc[i][j][3] + bias;
                us4 o; o.x = f2bf(v0); o.y = f2bf(v1); o.z = f2bf(v2); o.w = f2bf(v3);
                *reinterpret_cast<us4*>(e.fpT + (size_t)bb * 786432 + (size_t)gc * 1024 + nn) = o;
                float wqv = e.wq[gc], wkv = e.wk[gc];
                qp[0] = fmaf(v0, wqv, qp[0]); qp[1] = fmaf(v1, wqv, qp[1]);
                qp[2] = fmaf(v2, wqv, qp[2]); qp[3] = fmaf(v3, wqv, qp[3]);
                kp[0] = fmaf(v0, wkv, kp[0]); kp[1] = fmaf(v1, wkv, kp[1]);
                kp[2] = fmaf(v2, wkv, kp[2]); kp[3] = fmaf(v3, wkv, kp[3]);
            }
#pragma unroll
            for (int r = 0; r < 4; r++) {
                float q = qp[r], k = kp[r];
#pragma unroll
                for (int m = 1; m < 16; m <<= 1) { q += __shfl_xor(q, m); k += __shfl_xor(k, m); }
                if (lm == 0) { atomicAdd(e.qv + gr + r, q); atomicAdd(e.kv + gr + r, k); }
            }
        } else if constexpr (EPI == EPI_Y) {
            size_t grow = (size_t)blockIdx.z * 1024 + gr;
#pragma unroll
            for (int j = 0; j < 4; j++) {
                int gc = col0 + cw0 + j * 16 + lm;
#pragma unroll
                for (int r = 0; r < 4; r++)
                    e.catA[(grow + r) * 1536 + gc] = f2bf(acc[i][j][r]);
            }
        } else if constexpr (EPI == EPI_GATES) {
#pragma unroll
            for (int j = 0; j < 4; j++) {
                int gc = col0 + cw0 + j * 16 + lm;
                if (grp == 0) {
                    float bias = e.b1[gc] + e.b2[gc];      // b_uy + b_ux
#pragma unroll
                    for (int r = 0; r < 4; r++) {
                        size_t idx = (size_t)(gr + r) * 768 + gc;
                        e.ub_o[idx] = f2bf(1.f / (1.f + __expf(-(acc[i][j][r] + bias))));
                    }
                } else {
                    float bias = e.b3[gc] + e.b4[gc];      // b_ry + b_rx
#pragma unroll
                    for (int r = 0; r < 4; r++) {
                        size_t idx = (size_t)(gr + r) * 768 + gc;
                        float rr = 1.f / (1.f + __expf(-(acc[i][j][r] + bias)));
                        float xv = bf2f(e.xb[(size_t)(gr + r) * 1536 + gc]);
                        e.rxb_o[idx] = f2bf(rr * xv);
                    }
                }
            }
        } else {  // EPI_OUT: acc = y@Wty + rx@Wtx
#pragma unroll
            for (int j = 0; j < 4; j++) {
                int gc = col0 + cw0 + j * 16 + lm;
                float bias = e.b1[gc] + e.b2[gc];          // b_ty + b_tx
#pragma unroll
                for (int r = 0; r < 4; r++) {
                    size_t idx = (size_t)(gr + r) * 768 + gc;
                    float tt = fast_tanh(acc[i][j][r] + bias);
                    float uu = bf2f(e.ub[idx]);
                    float xv = bf2f(e.xb[(size_t)(gr + r) * 1536 + gc]);
                    __builtin_nontemporal_store((1.f - uu) * xv + uu * tt, e.of + idx);
                }
            }
        }
    }
}

// per-EPI symbols for rocprof attribution
__global__ __launch_bounds__(256) void gFPT(
    const u16* __restrict__ A1, const u16* __restrict__ B1, int K, int ldA1, int ldB1, Epi e) {
    g_body<EPI_FPT, 1>(A1, B1, nullptr, nullptr, K, ldA1, ldB1, 0, 0, 0, 0, e);
}
__global__ __launch_bounds__(256) void gY(
    const u16* __restrict__ A1, const u16* __restrict__ B1, int K, int ldA1, int ldB1,
    size_t zA, size_t zB, Epi e) {
    g_body<EPI_Y, 1>(A1, B1, nullptr, nullptr, K, ldA1, ldB1, 0, 0, zA, zB, e);
}
__global__ __launch_bounds__(256) void gGATES(
    const u16* __restrict__ A1, const u16* __restrict__ B1, int K, int ldA1, int ldB1, Epi e) {
    g_body<EPI_GATES, 1>(A1, B1, nullptr, nullptr, K, ldA1, ldB1, 0, 0, 0, 0, e);
}
__global__ __launch_bounds__(256) void gOUT(
    const u16* __restrict__ A1, const u16* __restrict__ B1,
    const u16* __restrict__ A2, const u16* __restrict__ B2,
    int K, int ldA1, int ldB1, int ldA2, int ldB2, Epi e) {
    g_body<EPI_OUT, 2>(A1, B1, A2, B2, K, ldA1, ldB1, ldA2, ldB2, 0, 0, e);
}

// ---------------- softmax: one wave per row, coalesced c-major layout ----------------
__global__ __launch_bounds__(256) void k_soft4(const float* __restrict__ adj,
                                               const float* __restrict__ qv,
                                               const float* __restrict__ kv,
                                               const float* __restrict__ bq,
                                               const float* __restrict__ bk,
                                               u16* __restrict__ attb) {
    int wv = threadIdx.x >> 6, lane = threadIdx.x & 63;
    int bn = blockIdx.x * 4 + wv;
    int b = bn >> 10;
    const float* adjrow = adj + (size_t)bn * 1024;
    const float* krow = kv + (b << 10);
    float q = qv[bn] + bq[0] + bk[0];

    float v[16];
#pragma unroll
    for (int c = 0; c < 4; c++) {
        float4 a4 = *reinterpret_cast<const float4*>(adjrow + c * 256 + lane * 4);
        float4 k4 = *reinterpret_cast<const float4*>(krow + c * 256 + lane * 4);
        float* vv = v + c * 4;
        vv[0] = q + k4.x + (1.f - a4.x) * -1.0e9f;
        vv[1] = q + k4.y + (1.f - a4.y) * -1.0e9f;
        vv[2] = q + k4.z + (1.f - a4.z) * -1.0e9f;
        vv[3] = q + k4.w + (1.f - a4.w) * -1.0e9f;
    }
#pragma unroll
    for (int t = 0; t < 16; t++) v[t] = v[t] >= 0.f ? v[t] : 0.01f * v[t];

    float mx = v[0];
#pragma unroll
    for (int t = 1; t < 16; t++) mx = fmaxf(mx, v[t]);
#pragma unroll
    for (int off = 32; off; off >>= 1) mx = fmaxf(mx, __shfl_xor(mx, off));

    float s = 0.f;
#pragma unroll
    for (int t = 0; t < 16; t++) { v[t] = __expf(v[t] - mx); s += v[t]; }
#pragma unroll
    for (int off = 32; off; off >>= 1) s += __shfl_xor(s, off);
    float inv = 1.f / s;

    u16* orow = attb + (size_t)bn * 1024;
#pragma unroll
    for (int c = 0; c < 4; c++) {
        us4 o;
        o.x = f2bf(v[c * 4 + 0] * inv); o.y = f2bf(v[c * 4 + 1] * inv);
        o.z = f2bf(v[c * 4 + 2] * inv); o.w = f2bf(v[c * 4 + 3] * inv);
        *reinterpret_cast<us4*>(orow + c * 256 + lane * 4) = o;
    }
}

extern "C" void kernel_launch(void* const* d_in, const int* in_sizes, int n_in,
                              void* d_out, int out_size, void* d_ws, size_t ws_size,
                              hipStream_t stream) {
    const float* x    = (const float*)d_in[0];
    const float* adj  = (const float*)d_in[1];
    const float* W_fc = (const float*)d_in[2];
    const float* b_fc = (const float*)d_in[3];
    const float* w_q  = (const float*)d_in[4];
    const float* b_q  = (const float*)d_in[5];
    const float* w_k  = (const float*)d_in[6];
    const float* b_k  = (const float*)d_in[7];
    const float* W_uy = (const float*)d_in[8];
    const float* b_uy = (const float*)d_in[9];
    const float* W_ux = (const float*)d_in[10];
    const float* b_ux = (const float*)d_in[11];
    const float* W_ry = (const float*)d_in[12];
    const float* b_ry = (const float*)d_in[13];
    const float* W_rx = (const float*)d_in[14];
    const float* b_rx = (const float*)d_in[15];
    const float* W_ty = (const float*)d_in[16];
    const float* b_ty = (const float*)d_in[17];
    const float* W_tx = (const float*)d_in[18];
    const float* b_tx = (const float*)d_in[19];

    char* ws = (char*)d_ws;
    u16*   CatA  = (u16*)  (ws + 0);            // 16384x1536 bf16  [y | x]   50331648
    u16*   Wfc_b = (u16*)  (ws + 50331648);     //  1179648
    u16*   Wty_b = (u16*)  (ws + 51511296);     //  1179648
    u16*   Wtx_b = (u16*)  (ws + 52690944);     //  1179648
    u16*   Wg    = (u16*)  (ws + 53870592);     // [ [Wuy|Wux] ; [Wry|Wrx] ] 4718592
    u16*   fpT   = (u16*)  (ws + 58589184);     // 16x768x1024 bf16          25165824
    float* qv    = (float*)(ws + 83755008);     // 16384 f32
    float* kv    = (float*)(ws + 83820544);     // 16384 f32
    u16*   attb  = (u16*)  (ws + 83886080);     // 16x1024x1024 bf16         33554432
    u16*   u_b   = (u16*)  (ws + 83886080);     // alias attb (dead after av)
    u16*   rxb   = (u16*)  (ws + 117440512);    // 16384x768 bf16            25165824

    cvtx<<<12288, 256, 0, stream>>>(x, CatA, qv);   // qv,kv contiguous: zeroes both

    WCvt wc;
    wc.s[0] = W_fc; wc.d[0] = Wfc_b;              wc.ld[0] = 768;
    wc.s[1] = W_ty; wc.d[1] = Wty_b;              wc.ld[1] = 768;
    wc.s[2] = W_tx; wc.d[2] = Wtx_b;              wc.ld[2] = 768;
    wc.s[3] = W_uy; wc.d[3] = Wg;                 wc.ld[3] = 1536;
    wc.s[4] = W_ux; wc.d[4] = Wg + 768;           wc.ld[4] = 1536;
    wc.s[5] = W_ry; wc.d[5] = Wg + 768 * 1536;    wc.ld[5] = 1536;
    wc.s[6] = W_rx; wc.d[6] = Wg + 768 * 1536 + 768; wc.ld[6] = 1536;
    cvtw<<<dim3(576, 7), 256, 0, stream>>>(wc);

    Epi e{};
    // feat_proj = x @ Wfc^T + b (A = CatA right half), + fused q/k partials
    e = Epi{}; e.b1 = b_fc; e.wq = w_q; e.wk = w_k; e.qv = qv; e.kv = kv; e.fpT = fpT;
    gFPT<<<dim3(64, 6), 256, 0, stream>>>(CatA + 768, Wfc_b, 768, 1536, 768, e);

    k_soft4<<<4096, 256, 0, stream>>>(adj, qv, kv, b_q, b_k, attb);

    // y = att @ fp  -> CatA left half
    e = Epi{}; e.catA = CatA;
    gY<<<dim3(4, 6, 16), 256, 0, stream>>>(attb, fpT, 1024, 1024, 1024,
                                           1048576, 786432, e);
    // gates: [u | r] = CatA @ [Wuy|Wux ; Wry|Wrx]^T
    e = Epi{}; e.b1 = b_uy; e.b2 = b_ux; e.b3 = b_ry; e.b4 = b_rx;
    e.xb = CatA + 768; e.ub_o = u_b; e.rxb_o = rxb;
    gGATES<<<dim3(64, 12), 256, 0, stream>>>(CatA, Wg, 1536, 1536, 1536, e);

    // out = (1-u)x + u*tanh(y@Wty^T + rx@Wtx^T + b_ty + b_tx)
    e = Epi{}; e.b1 = b_ty; e.b2 = b_tx; e.ub = u_b; e.xb = CatA + 768; e.of = (float*)d_out;
    gOUT<<<dim3(64, 6), 256, 0, stream>>>(CatA, Wty_b, rxb, Wtx_b,
                                          768, 1536, 768, 768, 768, e);
}

// Round 11
// 417.827 us; speedup vs baseline: 1.4195x; 1.4195x over previous
//
#include <hip/hip_runtime.h>
#include <cmath>

typedef __attribute__((ext_vector_type(8))) short bf16x8;
typedef __attribute__((ext_vector_type(4))) float f32x4;
typedef unsigned short u16;

struct __align__(8) us4 { u16 x, y, z, w; };

__device__ __forceinline__ u16 f2bf(float f) {
    union { float f; unsigned u; } v; v.f = f;
    unsigned u = v.u;
    u += 0x7fffu + ((u >> 16) & 1u);   // RNE
    return (u16)(u >> 16);
}
__device__ __forceinline__ float bf2f(u16 h) {
    union { unsigned u; float f; } v; v.u = ((unsigned)h) << 16;
    return v.f;
}
__device__ __forceinline__ float fast_tanh(float x) {
    // tanh(x) = sign(x) * (1 - t)/(1 + t), t = exp(-2|x|)  (t in (0,1]; no inf path)
    float t = __expf(-2.f * fabsf(x));
    float th = (1.f - t) / (1.f + t);
    return copysignf(th, x);
}
__device__ __forceinline__ f32x4 mfma16(bf16x8 a, bf16x8 b, f32x4 c) {
    return __builtin_amdgcn_mfma_f32_16x16x32_bf16(a, b, c, 0, 0, 0);
}
__device__ __forceinline__ void ld_lds16(const u16* g, u16* l) {
    __builtin_amdgcn_global_load_lds(
        (const __attribute__((address_space(1))) unsigned int*)g,
        (__attribute__((address_space(3))) unsigned int*)l, 16, 0, 0);
}

// ---------------- x -> CatA right half (bf16) + zero qv/kv ----------------
__global__ __launch_bounds__(256) void cvtx(const float* __restrict__ in,
                                            u16* __restrict__ CatA, float* __restrict__ qkz) {
    int i = blockIdx.x * 256 + threadIdx.x;         // over 3145728 float4 groups
    float4 f = reinterpret_cast<const float4*>(in)[i];
    us4 o; o.x = f2bf(f.x); o.y = f2bf(f.y); o.z = f2bf(f.z); o.w = f2bf(f.w);
    int row = i / 192, col = (i % 192) * 4;
    *reinterpret_cast<us4*>(CatA + (size_t)row * 1536 + 768 + col) = o;
    if (i < 8192) reinterpret_cast<float4*>(qkz)[i] = float4{0.f, 0.f, 0.f, 0.f};
}

// ---------------- 7 weight converts in one dispatch ----------------
struct WCvt { const float* s[7]; u16* d[7]; int ld[7]; };
__global__ __launch_bounds__(256) void cvtw(WCvt w) {
    int wi = blockIdx.y;
    int i = blockIdx.x * 256 + threadIdx.x;         // over 147456 float4 groups
    float4 f = reinterpret_cast<const float4*>(w.s[wi])[i];
    us4 o; o.x = f2bf(f.x); o.y = f2bf(f.y); o.z = f2bf(f.z); o.w = f2bf(f.w);
    int row = i / 192, col = (i % 192) * 4;
    *reinterpret_cast<us4*>(w.d[wi] + (size_t)row * w.ld[wi] + col) = o;
}

// =====================================================================
// m97-style GEMM, 128x128 tile, BK=64 — frozen round-0 main loop.
// EXACT round-6 configuration (measured best: 419.1us / 424.0us;
// gGATES 103.5us, MfmaUtil 33%, 0 conflicts, ~3 blk/CU reg-limited).
// Experiment ledger — all structural variants regressed, do not retry:
//   r1  4-deep ring @1blk/CU ......... -26%
//   r2  3-deep BK=32 ................. -9%
//   r4  4-phase lgkm-fenced @1blk/CU . -39%
//   r8  2-phase dbuf @2blk/CU ........ -11%
//   r10 256x128 tile (acc[8][4]) ..... -44% (128 AGPR -> 1 blk/CU)
// The 128^2/2x2/BK=64 config is Pareto-optimal for this family:
// LDS-ratio improvements cost registers (kills inter-block overlap),
// pipeline depth costs occupancy or phase overhead. ~33% MfmaUtil is
// the structural rate of 64KB-LDS-read/K-step at 3-way block overlap.
// Wins kept: fast_tanh (-16us), soft4 coalescing + NT store (-3us).
// =====================================================================
enum { EPI_FPT = 0, EPI_Y, EPI_GATES, EPI_OUT };

struct Epi {
    const float* b1; const float* b2; const float* b3; const float* b4;
    const float* wq; const float* wk; float* qv; float* kv;   // FPT
    u16* fpT;
    u16* catA;                                                 // Y
    const u16* xb;        // CatA+768 (stride 1536)
    u16* ub_o; u16* rxb_o;                                     // GATES
    const u16* ub; float* of;                                  // OUT
};

template<int EPI, int PH>
__device__ __forceinline__ void g128_body(
    const u16* __restrict__ A1, const u16* __restrict__ B1,
    const u16* __restrict__ A2, const u16* __restrict__ B2,
    int K, int ldA1, int ldB1, int ldA2, int ldB2,
    size_t zA, size_t zB, Epi e)
{
    __shared__ u16 lA[128 * 64];
    __shared__ u16 lB[128 * 64];

    const int t = threadIdx.x;
    const int w = t >> 6, lane = t & 63, lm = lane & 15, quad = lane >> 4;
    const int row0 = blockIdx.x * 128;
    int col0, grp = 0;
    if constexpr (EPI == EPI_GATES) { grp = blockIdx.y / 6; col0 = (blockIdx.y % 6) * 128; }
    else col0 = blockIdx.y * 128;

    // staging: linear chunk-id n = q*256 + t; LDS offset = n*16B (fits
    // wave-uniform base + lane*16). Global: row = row0 + q*32 + (t>>3),
    // chunk = (t&7) ^ ((t>>3)&7)  [XOR swizzle vs row&7].
    const int rs2 = t >> 3;                         // 0..31
    const int kc2 = (((t & 7) ^ (rs2 & 7)) * 8);
    u16* dA_[4]; u16* dB_[4];
#pragma unroll
    for (int q = 0; q < 4; q++) {
        dA_[q] = lA + q * 2048 + w * 512;
        dB_[q] = lB + q * 2048 + w * 512;
    }

    // compute map: wave (w&1) row-half, (w>>1) col-half
    const int rw0 = (w & 1) * 64, cw0 = (w >> 1) * 64;
    // LDS read: row R, logical k-half h chunk (quad+4h); stored at chunk^( R&7 ), R&7 == lm&7
    const int ch0 = ((quad) ^ (lm & 7)) * 8;
    const int ch1 = ((quad + 4) ^ (lm & 7)) * 8;
    int laB[4], lbB[4];
#pragma unroll
    for (int i = 0; i < 4; i++) laB[i] = (rw0 + i * 16 + lm) * 64;
#pragma unroll
    for (int j = 0; j < 4; j++) lbB[j] = (cw0 + j * 16 + lm) * 64;

    f32x4 acc[4][4] = {};
    bool first = true;

#pragma unroll
    for (int ph = 0; ph < PH; ph++) {
        const u16* As; const u16* Bs; int ldA, ldB;
        if (ph == 0) { As = A1 + (size_t)blockIdx.z * zA; Bs = B1 + (size_t)blockIdx.z * zB; ldA = ldA1; ldB = ldB1; }
        else         { As = A2; Bs = B2; ldA = ldA2; ldB = ldB2; }
        if constexpr (EPI == EPI_GATES) Bs += (size_t)grp * (768 * 1536);
        const u16* gA = As + (size_t)(row0 + rs2) * ldA + kc2;
        const u16* gB = Bs + (size_t)(col0 + rs2) * ldB + kc2;

        for (int k0 = 0; k0 < K; k0 += 64) {
            if (!first) __syncthreads();
            first = false;
#pragma unroll
            for (int q = 0; q < 4; q++) {
                ld_lds16(gA + (size_t)(q * 32) * ldA + k0, dA_[q]);
                ld_lds16(gB + (size_t)(q * 32) * ldB + k0, dB_[q]);
            }
            __syncthreads();

#pragma unroll
            for (int h = 0; h < 2; h++) {
                const int ch = h ? ch1 : ch0;
                bf16x8 a[4], b[4];
#pragma unroll
                for (int i = 0; i < 4; i++) a[i] = *reinterpret_cast<const bf16x8*>(lA + laB[i] + ch);
#pragma unroll
                for (int j = 0; j < 4; j++) b[j] = *reinterpret_cast<const bf16x8*>(lB + lbB[j] + ch);
#pragma unroll
                for (int i = 0; i < 4; i++)
#pragma unroll
                    for (int j = 0; j < 4; j++)
                        acc[i][j] = mfma16(a[i], b[j], acc[i][j]);
            }
        }
    }

    // ---------------- epilogue ----------------
#pragma unroll
    for (int i = 0; i < 4; i++) {
        const int gr = row0 + rw0 + i * 16 + quad * 4;   // local (per-z) row
        if constexpr (EPI == EPI_FPT) {
            float qp[4] = {}, kp[4] = {};
            int bb = gr >> 10, nn = gr & 1023;
#pragma unroll
            for (int j = 0; j < 4; j++) {
                int gc = col0 + cw0 + j * 16 + lm;
                float bias = e.b1[gc];
                float v0 = acc[i][j][0] + bias, v1 = acc[i][j][1] + bias;
                float v2 = acc[i][j][2] + bias, v3 = acc[i][j][3] + bias;
                us4 o; o.x = f2bf(v0); o.y = f2bf(v1); o.z = f2bf(v2); o.w = f2bf(v3);
                *reinterpret_cast<us4*>(e.fpT + (size_t)bb * 786432 + (size_t)gc * 1024 + nn) = o;
                float wqv = e.wq[gc], wkv = e.wk[gc];
                qp[0] = fmaf(v0, wqv, qp[0]); qp[1] = fmaf(v1, wqv, qp[1]);
                qp[2] = fmaf(v2, wqv, qp[2]); qp[3] = fmaf(v3, wqv, qp[3]);
                kp[0] = fmaf(v0, wkv, kp[0]); kp[1] = fmaf(v1, wkv, kp[1]);
                kp[2] = fmaf(v2, wkv, kp[2]); kp[3] = fmaf(v3, wkv, kp[3]);
            }
#pragma unroll
            for (int r = 0; r < 4; r++) {
                float q = qp[r], k = kp[r];
#pragma unroll
                for (int m = 1; m < 16; m <<= 1) { q += __shfl_xor(q, m); k += __shfl_xor(k, m); }
                if (lm == 0) { atomicAdd(e.qv + gr + r, q); atomicAdd(e.kv + gr + r, k); }
            }
        } else if constexpr (EPI == EPI_Y) {
            size_t grow = (size_t)blockIdx.z * 1024 + gr;
#pragma unroll
            for (int j = 0; j < 4; j++) {
                int gc = col0 + cw0 + j * 16 + lm;
#pragma unroll
                for (int r = 0; r < 4; r++)
                    e.catA[(grow + r) * 1536 + gc] = f2bf(acc[i][j][r]);
            }
        } else if constexpr (EPI == EPI_GATES) {
#pragma unroll
            for (int j = 0; j < 4; j++) {
                int gc = col0 + cw0 + j * 16 + lm;
                if (grp == 0) {
                    float bias = e.b1[gc] + e.b2[gc];      // b_uy + b_ux
#pragma unroll
                    for (int r = 0; r < 4; r++) {
                        size_t idx = (size_t)(gr + r) * 768 + gc;
                        e.ub_o[idx] = f2bf(1.f / (1.f + __expf(-(acc[i][j][r] + bias))));
                    }
                } else {
                    float bias = e.b3[gc] + e.b4[gc];      // b_ry + b_rx
#pragma unroll
                    for (int r = 0; r < 4; r++) {
                        size_t idx = (size_t)(gr + r) * 768 + gc;
                        float rr = 1.f / (1.f + __expf(-(acc[i][j][r] + bias)));
                        float xv = bf2f(e.xb[(size_t)(gr + r) * 1536 + gc]);
                        e.rxb_o[idx] = f2bf(rr * xv);
                    }
                }
            }
        } else {  // EPI_OUT: acc = y@Wty + rx@Wtx
#pragma unroll
            for (int j = 0; j < 4; j++) {
                int gc = col0 + cw0 + j * 16 + lm;
                float bias = e.b1[gc] + e.b2[gc];          // b_ty + b_tx
#pragma unroll
                for (int r = 0; r < 4; r++) {
                    size_t idx = (size_t)(gr + r) * 768 + gc;
                    float tt = fast_tanh(acc[i][j][r] + bias);
                    float uu = bf2f(e.ub[idx]);
                    float xv = bf2f(e.xb[(size_t)(gr + r) * 1536 + gc]);
                    __builtin_nontemporal_store((1.f - uu) * xv + uu * tt, e.of + idx);
                }
            }
        }
    }
}

// per-EPI symbols for rocprof attribution
__global__ __launch_bounds__(256) void gFPT(
    const u16* __restrict__ A1, const u16* __restrict__ B1, int K, int ldA1, int ldB1, Epi e) {
    g128_body<EPI_FPT, 1>(A1, B1, nullptr, nullptr, K, ldA1, ldB1, 0, 0, 0, 0, e);
}
__global__ __launch_bounds__(256) void gY(
    const u16* __restrict__ A1, const u16* __restrict__ B1, int K, int ldA1, int ldB1,
    size_t zA, size_t zB, Epi e) {
    g128_body<EPI_Y, 1>(A1, B1, nullptr, nullptr, K, ldA1, ldB1, 0, 0, zA, zB, e);
}
__global__ __launch_bounds__(256) void gGATES(
    const u16* __restrict__ A1, const u16* __restrict__ B1, int K, int ldA1, int ldB1, Epi e) {
    g128_body<EPI_GATES, 1>(A1, B1, nullptr, nullptr, K, ldA1, ldB1, 0, 0, 0, 0, e);
}
__global__ __launch_bounds__(256) void gOUT(
    const u16* __restrict__ A1, const u16* __restrict__ B1,
    const u16* __restrict__ A2, const u16* __restrict__ B2,
    int K, int ldA1, int ldB1, int ldA2, int ldB2, Epi e) {
    g128_body<EPI_OUT, 2>(A1, B1, A2, B2, K, ldA1, ldB1, ldA2, ldB2, 0, 0, e);
}

// ---------------- softmax: one wave per row, coalesced c-major layout ----------------
// lane owns elements {c*256 + lane*4 .. +3}: every load/store instruction
// covers a contiguous 1KB (f32) / 512B (bf16) span. Reductions are
// permutation-invariant over the row.
__global__ __launch_bounds__(256) void k_soft4(const float* __restrict__ adj,
                                               const float* __restrict__ qv,
                                               const float* __restrict__ kv,
                                               const float* __restrict__ bq,
                                               const float* __restrict__ bk,
                                               u16* __restrict__ attb) {
    int wv = threadIdx.x >> 6, lane = threadIdx.x & 63;
    int bn = blockIdx.x * 4 + wv;
    int b = bn >> 10;
    const float* adjrow = adj + (size_t)bn * 1024;
    const float* krow = kv + (b << 10);
    float q = qv[bn] + bq[0] + bk[0];

    float v[16];
#pragma unroll
    for (int c = 0; c < 4; c++) {
        float4 a4 = *reinterpret_cast<const float4*>(adjrow + c * 256 + lane * 4);
        float4 k4 = *reinterpret_cast<const float4*>(krow + c * 256 + lane * 4);
        float* vv = v + c * 4;
        vv[0] = q + k4.x + (1.f - a4.x) * -1.0e9f;
        vv[1] = q + k4.y + (1.f - a4.y) * -1.0e9f;
        vv[2] = q + k4.z + (1.f - a4.z) * -1.0e9f;
        vv[3] = q + k4.w + (1.f - a4.w) * -1.0e9f;
    }
#pragma unroll
    for (int t = 0; t < 16; t++) v[t] = v[t] >= 0.f ? v[t] : 0.01f * v[t];

    float mx = v[0];
#pragma unroll
    for (int t = 1; t < 16; t++) mx = fmaxf(mx, v[t]);
#pragma unroll
    for (int off = 32; off; off >>= 1) mx = fmaxf(mx, __shfl_xor(mx, off));

    float s = 0.f;
#pragma unroll
    for (int t = 0; t < 16; t++) { v[t] = __expf(v[t] - mx); s += v[t]; }
#pragma unroll
    for (int off = 32; off; off >>= 1) s += __shfl_xor(s, off);
    float inv = 1.f / s;

    u16* orow = attb + (size_t)bn * 1024;
#pragma unroll
    for (int c = 0; c < 4; c++) {
        us4 o;
        o.x = f2bf(v[c * 4 + 0] * inv); o.y = f2bf(v[c * 4 + 1] * inv);
        o.z = f2bf(v[c * 4 + 2] * inv); o.w = f2bf(v[c * 4 + 3] * inv);
        *reinterpret_cast<us4*>(orow + c * 256 + lane * 4) = o;
    }
}

extern "C" void kernel_launch(void* const* d_in, const int* in_sizes, int n_in,
                              void* d_out, int out_size, void* d_ws, size_t ws_size,
                              hipStream_t stream) {
    const float* x    = (const float*)d_in[0];
    const float* adj  = (const float*)d_in[1];
    const float* W_fc = (const float*)d_in[2];
    const float* b_fc = (const float*)d_in[3];
    const float* w_q  = (const float*)d_in[4];
    const float* b_q  = (const float*)d_in[5];
    const float* w_k  = (const float*)d_in[6];
    const float* b_k  = (const float*)d_in[7];
    const float* W_uy = (const float*)d_in[8];
    const float* b_uy = (const float*)d_in[9];
    const float* W_ux = (const float*)d_in[10];
    const float* b_ux = (const float*)d_in[11];
    const float* W_ry = (const float*)d_in[12];
    const float* b_ry = (const float*)d_in[13];
    const float* W_rx = (const float*)d_in[14];
    const float* b_rx = (const float*)d_in[15];
    const float* W_ty = (const float*)d_in[16];
    const float* b_ty = (const float*)d_in[17];
    const float* W_tx = (const float*)d_in[18];
    const float* b_tx = (const float*)d_in[19];

    char* ws = (char*)d_ws;
    u16*   CatA  = (u16*)  (ws + 0);            // 16384x1536 bf16  [y | x]   50331648
    u16*   Wfc_b = (u16*)  (ws + 50331648);     //  1179648
    u16*   Wty_b = (u16*)  (ws + 51511296);     //  1179648
    u16*   Wtx_b = (u16*)  (ws + 52690944);     //  1179648
    u16*   Wg    = (u16*)  (ws + 53870592);     // [ [Wuy|Wux] ; [Wry|Wrx] ] 4718592
    u16*   fpT   = (u16*)  (ws + 58589184);     // 16x768x1024 bf16          25165824
    float* qv    = (float*)(ws + 83755008);     // 16384 f32
    float* kv    = (float*)(ws + 83820544);     // 16384 f32
    u16*   attb  = (u16*)  (ws + 83886080);     // 16x1024x1024 bf16         33554432
    u16*   u_b   = (u16*)  (ws + 83886080);     // alias attb (dead after av)
    u16*   rxb   = (u16*)  (ws + 117440512);    // 16384x768 bf16            25165824

    cvtx<<<12288, 256, 0, stream>>>(x, CatA, qv);   // qv,kv contiguous: zeroes both

    WCvt wc;
    wc.s[0] = W_fc; wc.d[0] = Wfc_b;              wc.ld[0] = 768;
    wc.s[1] = W_ty; wc.d[1] = Wty_b;              wc.ld[1] = 768;
    wc.s[2] = W_tx; wc.d[2] = Wtx_b;              wc.ld[2] = 768;
    wc.s[3] = W_uy; wc.d[3] = Wg;                 wc.ld[3] = 1536;
    wc.s[4] = W_ux; wc.d[4] = Wg + 768;           wc.ld[4] = 1536;
    wc.s[5] = W_ry; wc.d[5] = Wg + 768 * 1536;    wc.ld[5] = 1536;
    wc.s[6] = W_rx; wc.d[6] = Wg + 768 * 1536 + 768; wc.ld[6] = 1536;
    cvtw<<<dim3(576, 7), 256, 0, stream>>>(wc);

    Epi e{};
    // feat_proj = x @ Wfc^T + b (A = CatA right half), + fused q/k partials
    e = Epi{}; e.b1 = b_fc; e.wq = w_q; e.wk = w_k; e.qv = qv; e.kv = kv; e.fpT = fpT;
    gFPT<<<dim3(128, 6), 256, 0, stream>>>(CatA + 768, Wfc_b, 768, 1536, 768, e);

    k_soft4<<<4096, 256, 0, stream>>>(adj, qv, kv, b_q, b_k, attb);

    // y = att @ fp  -> CatA left half
    e = Epi{}; e.catA = CatA;
    gY<<<dim3(8, 6, 16), 256, 0, stream>>>(attb, fpT, 1024, 1024, 1024,
                                           1048576, 786432, e);
    // gates: [u | r] = CatA @ [Wuy|Wux ; Wry|Wrx]^T
    e = Epi{}; e.b1 = b_uy; e.b2 = b_ux; e.b3 = b_ry; e.b4 = b_rx;
    e.xb = CatA + 768; e.ub_o = u_b; e.rxb_o = rxb;
    gGATES<<<dim3(128, 12), 256, 0, stream>>>(CatA, Wg, 1536, 1536, 1536, e);

    // out = (1-u)x + u*tanh(y@Wty^T + rx@Wtx^T + b_ty + b_tx)
    e = Epi{}; e.b1 = b_ty; e.b2 = b_tx; e.ub = u_b; e.xb = CatA + 768; e.of = (float*)d_out;
    gOUT<<<dim3(128, 6), 256, 0, stream>>>(CatA, Wty_b, rxb, Wtx_b,
                                           768, 1536, 768, 768, 768, e);
}